// Round 1
// baseline (866.143 us; speedup 1.0000x reference)
//
#include <hip/hip_runtime.h>
#include <cstddef>
#include <cstdint>

// Problem constants (fixed by harness shapes)
#define NTOK 8192      // N
#define CD   256       // C
#define HWPIX 16384    // H*W = 128*128
#define WIDTH 128
#define NSEQ 1024      // Ns = (128/4)^2

// ---------------------------------------------------------------------------
// 1. token2map scatter: segment-sum of [x_source, 1] into (B, HW, C) + (B, HW)
// ---------------------------------------------------------------------------
__global__ __launch_bounds__(256) void scatter_k(const float* __restrict__ xsrc,
        const float* __restrict__ loc, float* __restrict__ feat,
        float* __restrict__ maskr) {
    int token = blockIdx.x;            // 0 .. B*N-1
    int b = token >> 13;               // N = 8192
    int c = threadIdx.x;
    float lx = loc[token * 2 + 0];
    float ly = loc[token * 2 + 1];
    lx = fminf(fmaxf(lx, 0.f), 1.f) * 127.0f;   // * (W-1)
    ly = fminf(fmaxf(ly, 0.f), 1.f) * 127.0f;   // * (H-1)
    int ix = __float2int_rn(lx);       // round half-to-even, matches jnp.round
    int iy = __float2int_rn(ly);
    int p = b * HWPIX + iy * WIDTH + ix;
    atomicAdd(&feat[(size_t)p * CD + c], xsrc[(size_t)token * CD + c]);
    if (c == 0) atomicAdd(&maskr[p], 1.0f);
}

// ---------------------------------------------------------------------------
// 2. normalize: feat = feat/(m+1e-6) * (m>0); mbin = (m>0)
// ---------------------------------------------------------------------------
__global__ __launch_bounds__(256) void norm_mask_k(float* __restrict__ feat,
        const float* __restrict__ maskr, float* __restrict__ mbin) {
    int p = blockIdx.x;                // 0 .. B*HW-1
    int c = threadIdx.x;
    float m = maskr[p];
    float inv = 1.0f / (m + 1e-6f);
    float bin = (m > 0.f) ? 1.f : 0.f;
    feat[(size_t)p * CD + c] = feat[(size_t)p * CD + c] * inv * bin;
    if (c == 0) mbin[p] = bin;
}

// ---------------------------------------------------------------------------
// 3. 3x3 gaussian (sigma=2) filter of [feat, mask] + reconstruct
//    recon = feat + (1-m) * [ (gf/(gm+1e-6)) * (gm>0) ]
// ---------------------------------------------------------------------------
__global__ __launch_bounds__(256) void recon_k(const float* __restrict__ feat,
        const float* __restrict__ mbin, float* __restrict__ recon) {
    int p = blockIdx.x;                // b*HW + pix
    int b = p >> 14;
    int pix = p & 16383;
    int y = pix >> 7, x = pix & 127;
    int c = threadIdx.x;
    const float e1 = 0.882496902584595f;   // exp(-1/8)
    const float e2 = 0.778800783071405f;   // exp(-2/8)
    const float snorm = 1.0f / (1.0f + 4.0f * e1 + 4.0f * e2);
    float gf = 0.f, gm = 0.f;
    #pragma unroll
    for (int dy = -1; dy <= 1; dy++) {
        #pragma unroll
        for (int dx = -1; dx <= 1; dx++) {
            int yy = y + dy, xx = x + dx;
            if (yy < 0 || yy > 127 || xx < 0 || xx > 127) continue;
            int manh = (dy != 0) + (dx != 0);
            float w = (manh == 2) ? e2 : (manh == 1) ? e1 : 1.0f;
            int np_ = b * HWPIX + yy * WIDTH + xx;
            gf += w * feat[(size_t)np_ * CD + c];
            gm += w * mbin[np_];
        }
    }
    gf *= snorm; gm *= snorm;
    float f_int = (gm > 0.f) ? (gf / (gm + 1e-6f)) : 0.f;
    float m = mbin[p];
    recon[(size_t)p * CD + c] = feat[(size_t)p * CD + c] + (1.f - m) * f_int;
}

// ---------------------------------------------------------------------------
// 4a. gather non-overlapping 4x4 patches -> A matrix (2048 x 4096)
//     col layout: (kh*4+kw)*256 + ci
// ---------------------------------------------------------------------------
__global__ __launch_bounds__(256) void gather_k(const float* __restrict__ recon,
        float* __restrict__ apatch) {
    int r = blockIdx.x;                // 0..2047 = b*1024 + ph*32 + pw
    int b = r >> 10;
    int pp = r & 1023;
    int ph = pp >> 5, pw = pp & 31;
    int t = threadIdx.x;               // ci
    #pragma unroll
    for (int k16 = 0; k16 < 16; k16++) {
        int kh = k16 >> 2, kw = k16 & 3;
        int pix = (4 * ph + kh) * WIDTH + 4 * pw + kw;
        apatch[(size_t)r * 4096 + k16 * 256 + t] =
            recon[((size_t)b * HWPIX + pix) * CD + t];
    }
}

// 4b. transpose sr_w (co,ci,kh,kw) -> wT[co][(kh*4+kw)*256+ci]
__global__ __launch_bounds__(256) void wtrans_k(const float* __restrict__ srw,
        float* __restrict__ wT) {
    int idx = blockIdx.x * 256 + threadIdx.x;  // 0 .. 256*4096-1
    int co = idx >> 12;
    int rest = idx & 4095;
    int k16 = rest >> 8;
    int ci = rest & 255;
    int kh = k16 >> 2, kw = k16 & 3;
    wT[idx] = srw[(size_t)co * 4096 + ci * 16 + kh * 4 + kw];
}

// 4c. init C with bias (for split-K atomic accumulation)
__global__ __launch_bounds__(256) void init_bias_k(float* __restrict__ C,
        const float* __restrict__ bias) {
    C[(size_t)blockIdx.x * 256 + threadIdx.x] = bias[threadIdx.x];
}

// ---------------------------------------------------------------------------
// 5. generic fp32 GEMM: C[M][N] (+)= A[M][K] @ B[N][K]^T (+ bias)
//    64x64 tile, 4x4 microtile, TK=16. kSplit>1 -> atomicAdd partials.
//    All M,N multiples of 64; K multiple of 16.
// ---------------------------------------------------------------------------
__global__ __launch_bounds__(256) void sgemm_tn(const float* __restrict__ A,
        const float* __restrict__ B, const float* __restrict__ bias,
        float* __restrict__ C, int M, int Nn, int K, int kSplit) {
    __shared__ float As[16][68];   // [k][m], padded to break write conflicts
    __shared__ float Bs[16][68];   // [k][n]
    int tid = threadIdx.x;
    int m0 = blockIdx.y * 64, n0 = blockIdx.x * 64;
    int kchunk = K / kSplit;
    int k0 = blockIdx.z * kchunk;
    int tx = tid & 15, ty = tid >> 4;
    int lr = tid >> 2;             // 0..63 tile row
    int lk = (tid & 3) * 4;        // 0,4,8,12 k offset
    float acc[4][4];
    #pragma unroll
    for (int i = 0; i < 4; i++)
        #pragma unroll
        for (int j = 0; j < 4; j++) acc[i][j] = 0.f;
    const float* aBase = A + (size_t)(m0 + lr) * K + k0 + lk;
    const float* bBase = B + (size_t)(n0 + lr) * K + k0 + lk;
    for (int kk = 0; kk < kchunk; kk += 16) {
        float4 av = *(const float4*)(aBase + kk);
        float4 bv = *(const float4*)(bBase + kk);
        As[lk + 0][lr] = av.x; As[lk + 1][lr] = av.y;
        As[lk + 2][lr] = av.z; As[lk + 3][lr] = av.w;
        Bs[lk + 0][lr] = bv.x; Bs[lk + 1][lr] = bv.y;
        Bs[lk + 2][lr] = bv.z; Bs[lk + 3][lr] = bv.w;
        __syncthreads();
        #pragma unroll
        for (int k = 0; k < 16; k++) {
            float4 a  = *(const float4*)&As[k][ty * 4];
            float4 b4 = *(const float4*)&Bs[k][tx * 4];
            acc[0][0] += a.x * b4.x; acc[0][1] += a.x * b4.y;
            acc[0][2] += a.x * b4.z; acc[0][3] += a.x * b4.w;
            acc[1][0] += a.y * b4.x; acc[1][1] += a.y * b4.y;
            acc[1][2] += a.y * b4.z; acc[1][3] += a.y * b4.w;
            acc[2][0] += a.z * b4.x; acc[2][1] += a.z * b4.y;
            acc[2][2] += a.z * b4.z; acc[2][3] += a.z * b4.w;
            acc[3][0] += a.w * b4.x; acc[3][1] += a.w * b4.y;
            acc[3][2] += a.w * b4.z; acc[3][3] += a.w * b4.w;
        }
        __syncthreads();
    }
    #pragma unroll
    for (int i = 0; i < 4; i++) {
        size_t row = (size_t)(m0 + ty * 4 + i) * Nn;
        #pragma unroll
        for (int j = 0; j < 4; j++) {
            int col = n0 + tx * 4 + j;
            if (kSplit > 1) atomicAdd(&C[row + col], acc[i][j]);
            else C[row + col] = acc[i][j] + (bias ? bias[col] : 0.f);
        }
    }
}

// ---------------------------------------------------------------------------
// 6. LayerNorm over C=256, in place, one block (256 thr) per row
// ---------------------------------------------------------------------------
__global__ __launch_bounds__(256) void ln_k(float* __restrict__ xs,
        const float* __restrict__ w, const float* __restrict__ bvec) {
    int row = blockIdx.x;
    int c = threadIdx.x;
    float v = xs[(size_t)row * 256 + c];
    __shared__ float red[4];
    float s = v;
    #pragma unroll
    for (int o = 32; o >= 1; o >>= 1) s += __shfl_down(s, o, 64);
    if ((c & 63) == 0) red[c >> 6] = s;
    __syncthreads();
    float mean = (red[0] + red[1] + red[2] + red[3]) * (1.f / 256.f);
    __syncthreads();
    float d = v - mean;
    float s2 = d * d;
    #pragma unroll
    for (int o = 32; o >= 1; o >>= 1) s2 += __shfl_down(s2, o, 64);
    if ((c & 63) == 0) red[c >> 6] = s2;
    __syncthreads();
    float var = (red[0] + red[1] + red[2] + red[3]) * (1.f / 256.f);
    float r = 1.0f / sqrtf(var + 1e-5f);
    xs[(size_t)row * 256 + c] = d * r * w[c] + bvec[c];
}

// ---------------------------------------------------------------------------
// 7. attention: one thread per query row, online softmax over 1024 keys,
//    K/V tiles (128 x 32) staged in LDS (broadcast reads: all lanes same key)
// ---------------------------------------------------------------------------
__global__ __launch_bounds__(256) void attn_k(const float* __restrict__ qb,
        const float* __restrict__ kb, const float* __restrict__ vbuf,
        const float* __restrict__ conf, float* __restrict__ ob) {
    __shared__ float Ks[128 * 32];
    __shared__ float Vs[128 * 32];
    __shared__ float Cs[128];
    int bh = blockIdx.y;
    int b = bh >> 3, h = bh & 7;
    int n = blockIdx.x * 256 + threadIdx.x;
    int tid = threadIdx.x;
    const float* qp = qb + ((size_t)(b * NTOK + n)) * 256 + h * 32;
    float qr[32];
    #pragma unroll
    for (int i = 0; i < 8; i++) {
        float4 t = *(const float4*)(qp + i * 4);
        qr[i * 4] = t.x; qr[i * 4 + 1] = t.y; qr[i * 4 + 2] = t.z; qr[i * 4 + 3] = t.w;
    }
    float mmax = -3e38f, l = 0.f;
    float acc[32];
    #pragma unroll
    for (int d = 0; d < 32; d++) acc[d] = 0.f;
    const float scale = 0.17677669529663687f;   // 32^-0.5
    for (int t0 = 0; t0 < NSEQ; t0 += 128) {
        __syncthreads();
        #pragma unroll
        for (int i = 0; i < 4; i++) {
            int e = tid + i * 256;             // float4 unit 0..1023
            int m = e >> 3, d4 = (e & 7) * 4;
            size_t src = ((size_t)(b * NSEQ + t0 + m)) * 256 + h * 32 + d4;
            *(float4*)&Ks[m * 32 + d4] = *(const float4*)(kb + src);
            *(float4*)&Vs[m * 32 + d4] = *(const float4*)(vbuf + src);
        }
        if (tid < 128) Cs[tid] = conf[b * NSEQ + t0 + tid];
        __syncthreads();
        for (int m = 0; m < 128; m++) {
            const float* kr = &Ks[m * 32];
            float s0 = 0, s1 = 0, s2 = 0, s3 = 0;
            #pragma unroll
            for (int i = 0; i < 8; i++) {
                float4 kv = *(const float4*)(kr + i * 4);
                s0 += qr[i * 4] * kv.x;     s1 += qr[i * 4 + 1] * kv.y;
                s2 += qr[i * 4 + 2] * kv.z; s3 += qr[i * 4 + 3] * kv.w;
            }
            float s = ((s0 + s1) + (s2 + s3)) * scale + Cs[m];
            if (s > mmax) {
                float alpha = __expf(mmax - s);
                l *= alpha;
                #pragma unroll
                for (int d = 0; d < 32; d++) acc[d] *= alpha;
                mmax = s;
            }
            float p = __expf(s - mmax);
            l += p;
            const float* vr = &Vs[m * 32];
            #pragma unroll
            for (int i = 0; i < 8; i++) {
                float4 vv = *(const float4*)(vr + i * 4);
                acc[i * 4]     += p * vv.x; acc[i * 4 + 1] += p * vv.y;
                acc[i * 4 + 2] += p * vv.z; acc[i * 4 + 3] += p * vv.w;
            }
        }
    }
    float inv = 1.0f / l;
    float* op = ob + ((size_t)(b * NTOK + n)) * 256 + h * 32;
    #pragma unroll
    for (int i = 0; i < 8; i++) {
        float4 t;
        t.x = acc[i * 4] * inv;     t.y = acc[i * 4 + 1] * inv;
        t.z = acc[i * 4 + 2] * inv; t.w = acc[i * 4 + 3] * inv;
        *(float4*)(op + i * 4) = t;
    }
}

// ---------------------------------------------------------------------------
extern "C" void kernel_launch(void* const* d_in, const int* in_sizes, int n_in,
                              void* d_out, int out_size, void* d_ws, size_t ws_size,
                              hipStream_t stream) {
    const float* x        = (const float*)d_in[0];
    const float* x_source = (const float*)d_in[1];
    const float* loc      = (const float*)d_in[2];
    const float* conf     = (const float*)d_in[3];
    const float* Wq       = (const float*)d_in[4];
    const float* Wk       = (const float*)d_in[5];
    const float* Wv       = (const float*)d_in[6];
    const float* srw      = (const float*)d_in[7];
    const float* srb      = (const float*)d_in[8];
    const float* lnw      = (const float*)d_in[9];
    const float* lnb      = (const float*)d_in[10];
    const float* Wp       = (const float*)d_in[11];
    const float* bp       = (const float*)d_in[12];
    float* out = (float*)d_out;
    float* ws  = (float*)d_ws;

    // workspace layout (floats); apatch aliases feat, aout aliases recon
    float* feat     = ws;                      // 8,388,608  (B*HW*C)
    float* mask_raw = feat + 8388608;          // 32,768
    float* mbin     = mask_raw + 32768;        // 32,768
    float* recon    = mbin + 32768;            // 8,388,608
    float* wT       = recon + 8388608;         // 1,048,576  (256*4096)
    float* xsb      = wT + 1048576;            // 524,288    (2048*256)
    float* kbuf     = xsb + 524288;            // 524,288
    float* vbuf     = kbuf + 524288;           // 524,288
    float* qbuf     = vbuf + 524288;           // 4,194,304  (16384*256)
    float* apatch   = feat;                    // reuse after recon_k
    float* aout     = recon;                   // reuse after gather_k

    // zero the scatter accumulators (feat + mask_raw are adjacent)
    hipMemsetAsync(feat, 0, (size_t)(8388608 + 32768) * sizeof(float), stream);

    scatter_k  <<<16384, 256, 0, stream>>>(x_source, loc, feat, mask_raw);
    norm_mask_k<<<32768, 256, 0, stream>>>(feat, mask_raw, mbin);
    recon_k    <<<32768, 256, 0, stream>>>(feat, mbin, recon);
    wtrans_k   <<<4096,  256, 0, stream>>>(srw, wT);
    gather_k   <<<2048,  256, 0, stream>>>(recon, apatch);
    init_bias_k<<<2048,  256, 0, stream>>>(xsb, srb);
    // conv as GEMM (2048 x 256 x K=4096), split-K=4 for occupancy
    sgemm_tn<<<dim3(4, 32, 4), 256, 0, stream>>>(apatch, wT, nullptr, xsb,
                                                 2048, 256, 4096, 4);
    ln_k<<<2048, 256, 0, stream>>>(xsb, lnw, lnb);
    sgemm_tn<<<dim3(4, 32, 1),  256, 0, stream>>>(xsb, Wk, nullptr, kbuf,
                                                  2048, 256, 256, 1);
    sgemm_tn<<<dim3(4, 32, 1),  256, 0, stream>>>(xsb, Wv, nullptr, vbuf,
                                                  2048, 256, 256, 1);
    sgemm_tn<<<dim3(4, 256, 1), 256, 0, stream>>>(x, Wq, nullptr, qbuf,
                                                  16384, 256, 256, 1);
    attn_k<<<dim3(32, 16), 256, 0, stream>>>(qbuf, kbuf, vbuf, conf, aout);
    sgemm_tn<<<dim3(4, 256, 1), 256, 0, stream>>>(aout, Wp, bp, out,
                                                  16384, 256, 256, 1);
}

// Round 2
// 497.944 us; speedup vs baseline: 1.7394x; 1.7394x over previous
//
#include <hip/hip_runtime.h>
#include <hip/hip_bf16.h>
#include <cstddef>
#include <cstdint>

#define NTOK 8192      // N
#define CD   256       // C
#define HWPIX 16384    // H*W = 128*128
#define WIDTH 128
#define NSEQ 1024      // Ns

typedef __attribute__((ext_vector_type(8))) short bfrag;   // 8 bf16 = 4 VGPRs
typedef __attribute__((ext_vector_type(4))) float f32x4;

__device__ inline unsigned short f2bfu(float f) {
    __hip_bfloat16 h = __float2bfloat16(f);   // RTN
    unsigned short u;
    __builtin_memcpy(&u, &h, 2);
    return u;
}

// ---------------------------------------------------------------------------
// 1. token2map scatter
// ---------------------------------------------------------------------------
__global__ __launch_bounds__(256) void scatter_k(const float* __restrict__ xsrc,
        const float* __restrict__ loc, float* __restrict__ feat,
        float* __restrict__ maskr) {
    int token = blockIdx.x;
    int b = token >> 13;
    int c = threadIdx.x;
    float lx = loc[token * 2 + 0];
    float ly = loc[token * 2 + 1];
    lx = fminf(fmaxf(lx, 0.f), 1.f) * 127.0f;
    ly = fminf(fmaxf(ly, 0.f), 1.f) * 127.0f;
    int ix = __float2int_rn(lx);
    int iy = __float2int_rn(ly);
    int p = b * HWPIX + iy * WIDTH + ix;
    atomicAdd(&feat[(size_t)p * CD + c], xsrc[(size_t)token * CD + c]);
    if (c == 0) atomicAdd(&maskr[p], 1.0f);
}

// ---------------------------------------------------------------------------
// 2. normalize + binary mask
// ---------------------------------------------------------------------------
__global__ __launch_bounds__(256) void norm_mask_k(float* __restrict__ feat,
        const float* __restrict__ maskr, float* __restrict__ mbin) {
    int p = blockIdx.x;
    int c = threadIdx.x;
    float m = maskr[p];
    float inv = 1.0f / (m + 1e-6f);
    float bin = (m > 0.f) ? 1.f : 0.f;
    feat[(size_t)p * CD + c] = feat[(size_t)p * CD + c] * inv * bin;
    if (c == 0) mbin[p] = bin;
}

// ---------------------------------------------------------------------------
// 3. 3x3 gaussian reconstruct
// ---------------------------------------------------------------------------
__global__ __launch_bounds__(256) void recon_k(const float* __restrict__ feat,
        const float* __restrict__ mbin, float* __restrict__ recon) {
    int p = blockIdx.x;
    int b = p >> 14;
    int pix = p & 16383;
    int y = pix >> 7, x = pix & 127;
    int c = threadIdx.x;
    const float e1 = 0.882496902584595f;
    const float e2 = 0.778800783071405f;
    const float snorm = 1.0f / (1.0f + 4.0f * e1 + 4.0f * e2);
    float gf = 0.f, gm = 0.f;
    #pragma unroll
    for (int dy = -1; dy <= 1; dy++) {
        #pragma unroll
        for (int dx = -1; dx <= 1; dx++) {
            int yy = y + dy, xx = x + dx;
            if (yy < 0 || yy > 127 || xx < 0 || xx > 127) continue;
            int manh = (dy != 0) + (dx != 0);
            float w = (manh == 2) ? e2 : (manh == 1) ? e1 : 1.0f;
            int np_ = b * HWPIX + yy * WIDTH + xx;
            gf += w * feat[(size_t)np_ * CD + c];
            gm += w * mbin[np_];
        }
    }
    gf *= snorm; gm *= snorm;
    float f_int = (gm > 0.f) ? (gf / (gm + 1e-6f)) : 0.f;
    float m = mbin[p];
    recon[(size_t)p * CD + c] = feat[(size_t)p * CD + c] + (1.f - m) * f_int;
}

// ---------------------------------------------------------------------------
// 4a. gather 4x4 patches -> A matrix (2048 x 4096)
// ---------------------------------------------------------------------------
__global__ __launch_bounds__(256) void gather_k(const float* __restrict__ recon,
        float* __restrict__ apatch) {
    int r = blockIdx.x;
    int b = r >> 10;
    int pp = r & 1023;
    int ph = pp >> 5, pw = pp & 31;
    int t = threadIdx.x;
    #pragma unroll
    for (int k16 = 0; k16 < 16; k16++) {
        int kh = k16 >> 2, kw = k16 & 3;
        int pix = (4 * ph + kh) * WIDTH + 4 * pw + kw;
        apatch[(size_t)r * 4096 + k16 * 256 + t] =
            recon[((size_t)b * HWPIX + pix) * CD + t];
    }
}

// 4b. transpose sr_w
__global__ __launch_bounds__(256) void wtrans_k(const float* __restrict__ srw,
        float* __restrict__ wT) {
    int idx = blockIdx.x * 256 + threadIdx.x;
    int co = idx >> 12;
    int rest = idx & 4095;
    int k16 = rest >> 8;
    int ci = rest & 255;
    int kh = k16 >> 2, kw = k16 & 3;
    wT[idx] = srw[(size_t)co * 4096 + ci * 16 + kh * 4 + kw];
}

// 4c. init C with bias (for split-K)
__global__ __launch_bounds__(256) void init_bias_k(float* __restrict__ C,
        const float* __restrict__ bias) {
    C[(size_t)blockIdx.x * 256 + threadIdx.x] = bias[threadIdx.x];
}

// ---------------------------------------------------------------------------
// 5. fp32 GEMM: C[M][N] (+)= A[M][K] @ B[N][K]^T (+ bias)
// ---------------------------------------------------------------------------
__global__ __launch_bounds__(256) void sgemm_tn(const float* __restrict__ A,
        const float* __restrict__ B, const float* __restrict__ bias,
        float* __restrict__ C, int M, int Nn, int K, int kSplit) {
    __shared__ float As[16][68];
    __shared__ float Bs[16][68];
    int tid = threadIdx.x;
    int m0 = blockIdx.y * 64, n0 = blockIdx.x * 64;
    int kchunk = K / kSplit;
    int k0 = blockIdx.z * kchunk;
    int tx = tid & 15, ty = tid >> 4;
    int lr = tid >> 2;
    int lk = (tid & 3) * 4;
    float acc[4][4];
    #pragma unroll
    for (int i = 0; i < 4; i++)
        #pragma unroll
        for (int j = 0; j < 4; j++) acc[i][j] = 0.f;
    const float* aBase = A + (size_t)(m0 + lr) * K + k0 + lk;
    const float* bBase = B + (size_t)(n0 + lr) * K + k0 + lk;
    for (int kk = 0; kk < kchunk; kk += 16) {
        float4 av = *(const float4*)(aBase + kk);
        float4 bv = *(const float4*)(bBase + kk);
        As[lk + 0][lr] = av.x; As[lk + 1][lr] = av.y;
        As[lk + 2][lr] = av.z; As[lk + 3][lr] = av.w;
        Bs[lk + 0][lr] = bv.x; Bs[lk + 1][lr] = bv.y;
        Bs[lk + 2][lr] = bv.z; Bs[lk + 3][lr] = bv.w;
        __syncthreads();
        #pragma unroll
        for (int k = 0; k < 16; k++) {
            float4 a  = *(const float4*)&As[k][ty * 4];
            float4 b4 = *(const float4*)&Bs[k][tx * 4];
            acc[0][0] += a.x * b4.x; acc[0][1] += a.x * b4.y;
            acc[0][2] += a.x * b4.z; acc[0][3] += a.x * b4.w;
            acc[1][0] += a.y * b4.x; acc[1][1] += a.y * b4.y;
            acc[1][2] += a.y * b4.z; acc[1][3] += a.y * b4.w;
            acc[2][0] += a.z * b4.x; acc[2][1] += a.z * b4.y;
            acc[2][2] += a.z * b4.z; acc[2][3] += a.z * b4.w;
            acc[3][0] += a.w * b4.x; acc[3][1] += a.w * b4.y;
            acc[3][2] += a.w * b4.z; acc[3][3] += a.w * b4.w;
        }
        __syncthreads();
    }
    #pragma unroll
    for (int i = 0; i < 4; i++) {
        size_t row = (size_t)(m0 + ty * 4 + i) * Nn;
        #pragma unroll
        for (int j = 0; j < 4; j++) {
            int col = n0 + tx * 4 + j;
            if (kSplit > 1) atomicAdd(&C[row + col], acc[i][j]);
            else C[row + col] = acc[i][j] + (bias ? bias[col] : 0.f);
        }
    }
}

// ---------------------------------------------------------------------------
// 6. LayerNorm (C=256)
// ---------------------------------------------------------------------------
__global__ __launch_bounds__(256) void ln_k(float* __restrict__ xs,
        const float* __restrict__ w, const float* __restrict__ bvec) {
    int row = blockIdx.x;
    int c = threadIdx.x;
    float v = xs[(size_t)row * 256 + c];
    __shared__ float red[4];
    float s = v;
    #pragma unroll
    for (int o = 32; o >= 1; o >>= 1) s += __shfl_down(s, o, 64);
    if ((c & 63) == 0) red[c >> 6] = s;
    __syncthreads();
    float mean = (red[0] + red[1] + red[2] + red[3]) * (1.f / 256.f);
    __syncthreads();
    float d = v - mean;
    float s2 = d * d;
    #pragma unroll
    for (int o = 32; o >= 1; o >>= 1) s2 += __shfl_down(s2, o, 64);
    if ((c & 63) == 0) red[c >> 6] = s2;
    __syncthreads();
    float var = (red[0] + red[1] + red[2] + red[3]) * (1.f / 256.f);
    float r = 1.0f / sqrtf(var + 1e-5f);
    xs[(size_t)row * 256 + c] = d * r * w[c] + bvec[c];
}

// ---------------------------------------------------------------------------
// 7a. permute+convert [B*R][256] fp32 -> [B*8+h][R][32] bf16 (for Q and K)
// ---------------------------------------------------------------------------
__global__ __launch_bounds__(256) void prep_qk(const float* __restrict__ src,
        unsigned short* __restrict__ dst, int rshift) {
    int m = blockIdx.x;                // 0 .. B*R-1
    int c = threadIdx.x;               // h*32+d
    int b = m >> rshift;
    int r = m & ((1 << rshift) - 1);
    int h = c >> 5, d = c & 31;
    float v = src[(size_t)m * 256 + c];
    size_t di = ((((size_t)(b * 8 + h)) << rshift) + r) * 32 + d;
    dst[di] = f2bfu(v);
}

// 7b. transpose+convert vbuf [B*1024][256] fp32 -> Vt[(b*8+h)*32+d][1024] bf16
__global__ __launch_bounds__(256) void prep_vt(const float* __restrict__ vbuf,
        unsigned short* __restrict__ vt) {
    int bd = blockIdx.x;               // (b*8+h)*32 + d, 512 blocks
    int b = bd >> 8;
    int rest = bd & 255;
    int h = rest >> 5, d = rest & 31;
    int k0 = threadIdx.x * 4;
    ushort4 o;
    o.x = f2bfu(vbuf[((size_t)(b * NSEQ + k0 + 0)) * 256 + h * 32 + d]);
    o.y = f2bfu(vbuf[((size_t)(b * NSEQ + k0 + 1)) * 256 + h * 32 + d]);
    o.z = f2bfu(vbuf[((size_t)(b * NSEQ + k0 + 2)) * 256 + h * 32 + d]);
    o.w = f2bfu(vbuf[((size_t)(b * NSEQ + k0 + 3)) * 256 + h * 32 + d]);
    *(ushort4*)&vt[(size_t)bd * NSEQ + k0] = o;
}

// ---------------------------------------------------------------------------
// 8. MFMA flash attention.
//    Block = 4 waves, each wave owns 32 q rows of one (b,h); loops 16 key
//    tiles of 64. K/V frags load straight from global bf16 (L1/L2-resident),
//    P transits C-layout -> A-layout through a per-wave-private LDS region
//    (stride 72 bf16 = 144 B: 16B-aligned b128 reads, balanced banks).
//    No __syncthreads anywhere.
// ---------------------------------------------------------------------------
__global__ __launch_bounds__(256) void attn_mfma(
        const unsigned short* __restrict__ Qb,   // [bh][8192][32]
        const unsigned short* __restrict__ Kb,   // [bh][1024][32]
        const unsigned short* __restrict__ Vt,   // [bh][32][1024]
        const float* __restrict__ conf,          // [b][1024]
        float* __restrict__ ob) {                // [b*8192+n][256]
    __shared__ __align__(16) unsigned short Pl[4 * 2304];  // 4 waves * 2*16*72
    const float scale = 0.17677669529663687f;   // 32^-0.5
    int tid  = threadIdx.x;
    int wave = tid >> 6;
    int lane = tid & 63;
    int m15  = lane & 15;
    int quad = lane >> 4;
    int bh = blockIdx.y;
    int b  = bh >> 3;
    int h  = bh & 7;
    int qbase = blockIdx.x * 128 + wave * 32;

    const unsigned short* qp = Qb + ((size_t)bh * NTOK + qbase) * 32;
    bfrag Qa0 = *(const bfrag*)(qp + (size_t)m15 * 32 + quad * 8);
    bfrag Qa1 = *(const bfrag*)(qp + (size_t)(16 + m15) * 32 + quad * 8);

    const unsigned short* kp = Kb + (size_t)bh * NSEQ * 32;
    const unsigned short* vp = Vt + (size_t)bh * 32 * NSEQ;
    const float* cp = conf + b * NSEQ;
    unsigned short* Pw = Pl + wave * 2304;

    f32x4 O[2][2];
    float mrow[2][4], lrow[2][4];
    #pragma unroll
    for (int t = 0; t < 2; t++) {
        #pragma unroll
        for (int dt = 0; dt < 2; dt++)
            O[t][dt] = (f32x4){0.f, 0.f, 0.f, 0.f};
        #pragma unroll
        for (int r = 0; r < 4; r++) { mrow[t][r] = -3.0e38f; lrow[t][r] = 0.f; }
    }
    f32x4 zero = (f32x4){0.f, 0.f, 0.f, 0.f};

    for (int t0 = 0; t0 < NSEQ; t0 += 64) {
        // ---- S = Q K^T  (8 MFMAs) ----
        f32x4 S[2][4];
        #pragma unroll
        for (int sub = 0; sub < 4; sub++) {
            bfrag kf = *(const bfrag*)(kp +
                (size_t)(t0 + sub * 16 + m15) * 32 + quad * 8);
            S[0][sub] = __builtin_amdgcn_mfma_f32_16x16x32_bf16(Qa0, kf, zero, 0, 0, 0);
            S[1][sub] = __builtin_amdgcn_mfma_f32_16x16x32_bf16(Qa1, kf, zero, 0, 0, 0);
        }
        float cf[4];
        #pragma unroll
        for (int sub = 0; sub < 4; sub++) cf[sub] = cp[t0 + sub * 16 + m15];
        #pragma unroll
        for (int t = 0; t < 2; t++)
            #pragma unroll
            for (int sub = 0; sub < 4; sub++)
                #pragma unroll
                for (int r = 0; r < 4; r++)
                    S[t][sub][r] = S[t][sub][r] * scale + cf[sub];
        // ---- online softmax ----
        #pragma unroll
        for (int t = 0; t < 2; t++) {
            #pragma unroll
            for (int r = 0; r < 4; r++) {
                float v = fmaxf(fmaxf(S[t][0][r], S[t][1][r]),
                                fmaxf(S[t][2][r], S[t][3][r]));
                v = fmaxf(v, __shfl_xor(v, 1, 64));
                v = fmaxf(v, __shfl_xor(v, 2, 64));
                v = fmaxf(v, __shfl_xor(v, 4, 64));
                v = fmaxf(v, __shfl_xor(v, 8, 64));
                float mnew = fmaxf(mrow[t][r], v);
                float alpha = __expf(mrow[t][r] - mnew);
                mrow[t][r] = mnew;
                lrow[t][r] *= alpha;
                O[t][0][r] *= alpha;
                O[t][1][r] *= alpha;
                float rs = 0.f;
                #pragma unroll
                for (int sub = 0; sub < 4; sub++) {
                    float p = __expf(S[t][sub][r] - mnew);
                    rs += p;
                    Pw[t * 1152 + (quad * 4 + r) * 72 + sub * 16 + m15] = f2bfu(p);
                }
                rs += __shfl_xor(rs, 1, 64);
                rs += __shfl_xor(rs, 2, 64);
                rs += __shfl_xor(rs, 4, 64);
                rs += __shfl_xor(rs, 8, 64);
                lrow[t][r] += rs;
            }
        }
        // ---- O += P V  (8 MFMAs); same-wave LDS RAW, compiler waits lgkm ----
        #pragma unroll
        for (int kf2 = 0; kf2 < 2; kf2++) {
            bfrag Pa0 = *(const bfrag*)(Pw + 0 * 1152 + m15 * 72 + kf2 * 32 + quad * 8);
            bfrag Pa1 = *(const bfrag*)(Pw + 1 * 1152 + m15 * 72 + kf2 * 32 + quad * 8);
            #pragma unroll
            for (int dt = 0; dt < 2; dt++) {
                bfrag vf = *(const bfrag*)(vp +
                    (size_t)(dt * 16 + m15) * NSEQ + t0 + kf2 * 32 + quad * 8);
                O[0][dt] = __builtin_amdgcn_mfma_f32_16x16x32_bf16(Pa0, vf, O[0][dt], 0, 0, 0);
                O[1][dt] = __builtin_amdgcn_mfma_f32_16x16x32_bf16(Pa1, vf, O[1][dt], 0, 0, 0);
            }
        }
    }
    // ---- epilogue: O/l, store to [b*8192+n][256] fp32 ----
    #pragma unroll
    for (int t = 0; t < 2; t++) {
        #pragma unroll
        for (int r = 0; r < 4; r++) {
            float inv = 1.0f / lrow[t][r];
            int n = qbase + t * 16 + quad * 4 + r;
            size_t base = ((size_t)(b * NTOK + n)) * 256 + h * 32;
            ob[base + 0  + m15] = O[t][0][r] * inv;
            ob[base + 16 + m15] = O[t][1][r] * inv;
        }
    }
}

// ---------------------------------------------------------------------------
extern "C" void kernel_launch(void* const* d_in, const int* in_sizes, int n_in,
                              void* d_out, int out_size, void* d_ws, size_t ws_size,
                              hipStream_t stream) {
    const float* x        = (const float*)d_in[0];
    const float* x_source = (const float*)d_in[1];
    const float* loc      = (const float*)d_in[2];
    const float* conf     = (const float*)d_in[3];
    const float* Wq       = (const float*)d_in[4];
    const float* Wk       = (const float*)d_in[5];
    const float* Wv       = (const float*)d_in[6];
    const float* srw      = (const float*)d_in[7];
    const float* srb      = (const float*)d_in[8];
    const float* lnw      = (const float*)d_in[9];
    const float* lnb      = (const float*)d_in[10];
    const float* Wp       = (const float*)d_in[11];
    const float* bp       = (const float*)d_in[12];
    float* out = (float*)d_out;
    float* ws  = (float*)d_ws;

    // workspace layout (floats)
    float* feat     = ws;                      // 8,388,608  (B*HW*C)
    float* mask_raw = feat + 8388608;          // 32,768
    float* mbin     = mask_raw + 32768;        // 32,768
    float* recon    = mbin + 32768;            // 8,388,608
    float* wT       = recon + 8388608;         // 1,048,576
    float* xsb      = wT + 1048576;            // 524,288
    float* kbuf     = xsb + 524288;            // 524,288
    float* vbuf     = kbuf + 524288;           // 524,288
    float* qbuf     = vbuf + 524288;           // 4,194,304
    float* apatch   = feat;                    // alias (feat dead after conv)
    float* aout     = recon;                   // alias (recon dead after gather)
    // bf16 buffers carved out of feat region (dead after conv GEMM)
    unsigned short* Qbf = (unsigned short*)feat;               // 4,194,304 u16
    unsigned short* Kbf = (unsigned short*)(feat + 2097152);   //   524,288 u16
    unsigned short* Vtb = (unsigned short*)(feat + 2359296);   //   524,288 u16

    hipMemsetAsync(feat, 0, (size_t)(8388608 + 32768) * sizeof(float), stream);

    scatter_k  <<<16384, 256, 0, stream>>>(x_source, loc, feat, mask_raw);
    norm_mask_k<<<32768, 256, 0, stream>>>(feat, mask_raw, mbin);
    recon_k    <<<32768, 256, 0, stream>>>(feat, mbin, recon);
    wtrans_k   <<<4096,  256, 0, stream>>>(srw, wT);
    gather_k   <<<2048,  256, 0, stream>>>(recon, apatch);
    init_bias_k<<<2048,  256, 0, stream>>>(xsb, srb);
    sgemm_tn<<<dim3(4, 32, 4), 256, 0, stream>>>(apatch, wT, nullptr, xsb,
                                                 2048, 256, 4096, 4);
    ln_k<<<2048, 256, 0, stream>>>(xsb, lnw, lnb);
    sgemm_tn<<<dim3(4, 32, 1),  256, 0, stream>>>(xsb, Wk, nullptr, kbuf,
                                                  2048, 256, 256, 1);
    sgemm_tn<<<dim3(4, 32, 1),  256, 0, stream>>>(xsb, Wv, nullptr, vbuf,
                                                  2048, 256, 256, 1);
    sgemm_tn<<<dim3(4, 256, 1), 256, 0, stream>>>(x, Wq, nullptr, qbuf,
                                                  16384, 256, 256, 1);
    prep_qk<<<16384, 256, 0, stream>>>(qbuf, Qbf, 13);
    prep_qk<<<2048,  256, 0, stream>>>(kbuf, Kbf, 10);
    prep_vt<<<512,   256, 0, stream>>>(vbuf, Vtb);
    attn_mfma<<<dim3(64, 16), 256, 0, stream>>>(Qbf, Kbf, Vtb, conf, aout);
    sgemm_tn<<<dim3(4, 256, 1), 256, 0, stream>>>(aout, Wp, bp, out,
                                                  16384, 256, 256, 1);
}

// Round 3
// 363.340 us; speedup vs baseline: 2.3838x; 1.3705x over previous
//
#include <hip/hip_runtime.h>
#include <hip/hip_bf16.h>
#include <cstddef>
#include <cstdint>

#define NTOK 8192      // N
#define CD   256       // C
#define HWPIX 16384    // H*W = 128*128
#define WIDTH 128
#define NSEQ 1024      // Ns

typedef __attribute__((ext_vector_type(8))) short bfrag;   // 8 bf16 = 4 VGPRs
typedef __attribute__((ext_vector_type(4))) float f32x4;

__device__ inline unsigned short f2bfu(float f) {
    __hip_bfloat16 h = __float2bfloat16(f);   // RTN
    unsigned short u;
    __builtin_memcpy(&u, &h, 2);
    return u;
}
// RTN to bf16 in the HIGH 16 bits of the returned u32 (p not NaN, |p| << 3e38)
__device__ inline unsigned int rtn16(float f) {
    unsigned int u = __builtin_bit_cast(unsigned int, f);
    return u + 0x7fffu + ((u >> 16) & 1u);
}
__device__ inline float bits2f(unsigned int u) {
    return __builtin_bit_cast(float, u);
}

// ---------------------------------------------------------------------------
// 1. token2map scatter
// ---------------------------------------------------------------------------
__global__ __launch_bounds__(256) void scatter_k(const float* __restrict__ xsrc,
        const float* __restrict__ loc, float* __restrict__ feat,
        float* __restrict__ maskr) {
    int token = blockIdx.x;
    int b = token >> 13;
    int c = threadIdx.x;
    float lx = loc[token * 2 + 0];
    float ly = loc[token * 2 + 1];
    lx = fminf(fmaxf(lx, 0.f), 1.f) * 127.0f;
    ly = fminf(fmaxf(ly, 0.f), 1.f) * 127.0f;
    int ix = __float2int_rn(lx);
    int iy = __float2int_rn(ly);
    int p = b * HWPIX + iy * WIDTH + ix;
    atomicAdd(&feat[(size_t)p * CD + c], xsrc[(size_t)token * CD + c]);
    if (c == 0) atomicAdd(&maskr[p], 1.0f);
}

// ---------------------------------------------------------------------------
// 2. fused normalize + 3x3 gaussian reconstruct + 4x4 patch gather -> bf16 A
//    one block per pixel; 9 neighbor weights computed once in LDS
// ---------------------------------------------------------------------------
__global__ __launch_bounds__(256) void recon_fused(const float* __restrict__ feat,
        const float* __restrict__ maskr, unsigned short* __restrict__ apatch) {
    __shared__ float sw[9];    // g_j*snorm*inv_j*bin_j
    __shared__ float sgb[9];   // g_j*snorm*bin_j
    __shared__ int   snp[9];   // neighbor pixel index
    __shared__ float sci;      // center inv*bin
    __shared__ float sbc;      // center bin
    int p = blockIdx.x;
    int b = p >> 14;
    int pix = p & 16383;
    int y = pix >> 7, x = pix & 127;
    int c = threadIdx.x;
    const float e1 = 0.882496902584595f;   // exp(-1/8)
    const float e2 = 0.778800783071405f;   // exp(-2/8)
    const float snorm = 1.0f / (1.0f + 4.0f * e1 + 4.0f * e2);
    if (c < 9) {
        int dy = c / 3 - 1, dx = c % 3 - 1;
        int yy = y + dy, xx = x + dx;
        bool valid = (yy >= 0 && yy <= 127 && xx >= 0 && xx <= 127);
        int np_ = valid ? (b * HWPIX + yy * WIDTH + xx) : p;
        int manh = (dy != 0) + (dx != 0);
        float g = ((manh == 2) ? e2 : (manh == 1) ? e1 : 1.0f) * snorm;
        float m = maskr[np_];
        float bin = (m > 0.f) ? 1.f : 0.f;
        float inv = 1.0f / (m + 1e-6f);
        float vb = valid ? bin : 0.f;
        sw[c]  = g * vb * inv;
        sgb[c] = g * vb;
        snp[c] = np_;
        if (c == 4) { sci = bin * inv; sbc = bin; }
    }
    __syncthreads();
    float gm = ((sgb[0] + sgb[1]) + (sgb[2] + sgb[3])) +
               ((sgb[4] + sgb[5]) + (sgb[6] + sgb[7])) + sgb[8];
    float gf = 0.f;
    #pragma unroll
    for (int j = 0; j < 9; j++)
        gf += sw[j] * feat[(size_t)snp[j] * CD + c];
    float f_int = (gm > 0.f) ? (gf / (gm + 1e-6f)) : 0.f;
    float fc = feat[(size_t)p * CD + c] * sci;
    float res = fc + (1.f - sbc) * f_int;
    // patch layout: row r = b*1024 + (y/4)*32 + (x/4); col = ((y%4)*4+(x%4))*256 + c
    int r = b * 1024 + (y >> 2) * 32 + (x >> 2);
    int k16 = (y & 3) * 4 + (x & 3);
    apatch[(size_t)r * 4096 + k16 * 256 + c] = f2bfu(res);
}

// ---------------------------------------------------------------------------
// 3. transpose sr_w -> bf16 wT[co][(kh*4+kw)*256+ci]
// ---------------------------------------------------------------------------
__global__ __launch_bounds__(256) void wtrans_k(const float* __restrict__ srw,
        unsigned short* __restrict__ wT) {
    int idx = blockIdx.x * 256 + threadIdx.x;
    int co = idx >> 12;
    int rest = idx & 4095;
    int k16 = rest >> 8;
    int ci = rest & 255;
    int kh = k16 >> 2, kw = k16 & 3;
    wT[idx] = f2bfu(srw[(size_t)co * 4096 + ci * 16 + kh * 4 + kw]);
}

// 4. generic fp32 -> bf16 convert (n multiple of 1024, grid = n/1024)
__global__ __launch_bounds__(256) void cvt_bf16(const float* __restrict__ s,
        unsigned short* __restrict__ d) {
    int i = (blockIdx.x * 256 + threadIdx.x) * 4;
    float4 v = *(const float4*)(s + i);
    ushort4 o;
    o.x = f2bfu(v.x); o.y = f2bfu(v.y); o.z = f2bfu(v.z); o.w = f2bfu(v.w);
    *(ushort4*)(d + i) = o;
}

// 5. Wp -> split B' [256][768]: [bh | bl | bh]
__global__ __launch_bounds__(256) void prep_wp(const float* __restrict__ Wp,
        unsigned short* __restrict__ wpb) {
    int n = blockIdx.x, t = threadIdx.x;
    float w = Wp[n * 256 + t];
    unsigned short hu = f2bfu(w);
    float hf = bits2f(((unsigned int)hu) << 16);
    unsigned short lu = f2bfu(w - hf);
    wpb[n * 768 + t]       = hu;
    wpb[n * 768 + 256 + t] = lu;
    wpb[n * 768 + 512 + t] = hu;
}

// 6. init C with bias (for split-K atomic accumulation)
__global__ __launch_bounds__(256) void init_bias_k(float* __restrict__ C,
        const float* __restrict__ bias) {
    C[(size_t)blockIdx.x * 256 + threadIdx.x] = bias[threadIdx.x];
}

// ---------------------------------------------------------------------------
// 7. bf16 MFMA GEMM: C[M][N] (+)= A[M][K] @ B[N][K]^T (+bias)
//    128x128 tile, 4 waves (2x2 of 64x64), BK=32. kSplit>1 -> atomicAdd.
// ---------------------------------------------------------------------------
__global__ __launch_bounds__(256) void bgemm(const unsigned short* __restrict__ A,
        const unsigned short* __restrict__ B, const float* __restrict__ bias,
        float* __restrict__ C, int M, int N, int K, int kSplit) {
    __shared__ __align__(16) unsigned short As[128 * 32];
    __shared__ __align__(16) unsigned short Bs[128 * 32];
    int tid = threadIdx.x;
    int wave = tid >> 6, lane = tid & 63, m15 = lane & 15, quad = lane >> 4;
    int wr = (wave >> 1) * 64, wc = (wave & 1) * 64;
    int m0 = blockIdx.y * 128, n0 = blockIdx.x * 128;
    int kchunk = K / kSplit, k0 = blockIdx.z * kchunk;
    int srow = tid >> 2, sko = (tid & 3) * 8;
    f32x4 acc[4][4];
    #pragma unroll
    for (int i = 0; i < 4; i++)
        #pragma unroll
        for (int j = 0; j < 4; j++) acc[i][j] = (f32x4){0.f, 0.f, 0.f, 0.f};
    const unsigned short* Ag = A + (size_t)(m0 + srow) * K + k0 + sko;
    const unsigned short* Bg = B + (size_t)(n0 + srow) * K + k0 + sko;
    for (int kk = 0; kk < kchunk; kk += 32) {
        bfrag a0 = *(const bfrag*)(Ag + kk);
        bfrag a1 = *(const bfrag*)(Ag + (size_t)64 * K + kk);
        bfrag b0 = *(const bfrag*)(Bg + kk);
        bfrag b1 = *(const bfrag*)(Bg + (size_t)64 * K + kk);
        __syncthreads();   // prior frag reads done before overwrite
        *(bfrag*)&As[srow * 32 + sko] = a0;
        *(bfrag*)&As[(srow + 64) * 32 + sko] = a1;
        *(bfrag*)&Bs[srow * 32 + sko] = b0;
        *(bfrag*)&Bs[(srow + 64) * 32 + sko] = b1;
        __syncthreads();
        bfrag af[4], bfr[4];
        #pragma unroll
        for (int mi = 0; mi < 4; mi++)
            af[mi] = *(const bfrag*)&As[(wr + mi * 16 + m15) * 32 + quad * 8];
        #pragma unroll
        for (int ni = 0; ni < 4; ni++)
            bfr[ni] = *(const bfrag*)&Bs[(wc + ni * 16 + m15) * 32 + quad * 8];
        #pragma unroll
        for (int mi = 0; mi < 4; mi++)
            #pragma unroll
            for (int ni = 0; ni < 4; ni++)
                acc[mi][ni] = __builtin_amdgcn_mfma_f32_16x16x32_bf16(
                                  af[mi], bfr[ni], acc[mi][ni], 0, 0, 0);
    }
    #pragma unroll
    for (int mi = 0; mi < 4; mi++) {
        #pragma unroll
        for (int i = 0; i < 4; i++) {
            size_t row = (size_t)(m0 + wr + mi * 16 + quad * 4 + i) * N;
            #pragma unroll
            for (int ni = 0; ni < 4; ni++) {
                int col = n0 + wc + ni * 16 + m15;
                float v = acc[mi][ni][i];
                if (kSplit > 1) atomicAdd(&C[row + col], v);
                else C[row + col] = v + (bias ? bias[col] : 0.f);
            }
        }
    }
}

// ---------------------------------------------------------------------------
// 8. LayerNorm (C=256), fp32 in -> bf16 out
// ---------------------------------------------------------------------------
__global__ __launch_bounds__(256) void ln_k(const float* __restrict__ xs,
        const float* __restrict__ w, const float* __restrict__ bvec,
        unsigned short* __restrict__ outb) {
    int row = blockIdx.x;
    int c = threadIdx.x;
    float v = xs[(size_t)row * 256 + c];
    __shared__ float red[4];
    float s = v;
    #pragma unroll
    for (int o = 32; o >= 1; o >>= 1) s += __shfl_down(s, o, 64);
    if ((c & 63) == 0) red[c >> 6] = s;
    __syncthreads();
    float mean = (red[0] + red[1] + red[2] + red[3]) * (1.f / 256.f);
    __syncthreads();
    float d = v - mean;
    float s2 = d * d;
    #pragma unroll
    for (int o = 32; o >= 1; o >>= 1) s2 += __shfl_down(s2, o, 64);
    if ((c & 63) == 0) red[c >> 6] = s2;
    __syncthreads();
    float var = (red[0] + red[1] + red[2] + red[3]) * (1.f / 256.f);
    float r = 1.0f / sqrtf(var + 1e-5f);
    outb[(size_t)row * 256 + c] = f2bfu(d * r * w[c] + bvec[c]);
}

// ---------------------------------------------------------------------------
// 9a. permute+convert [B*R][256] fp32 -> [b*8+h][R][32] bf16 (Q and K)
// ---------------------------------------------------------------------------
__global__ __launch_bounds__(256) void prep_qk(const float* __restrict__ src,
        unsigned short* __restrict__ dst, int rshift) {
    int m = blockIdx.x;
    int c = threadIdx.x;
    int b = m >> rshift;
    int r = m & ((1 << rshift) - 1);
    int h = c >> 5, d = c & 31;
    float v = src[(size_t)m * 256 + c];
    size_t di = ((((size_t)(b * 8 + h)) << rshift) + r) * 32 + d;
    dst[di] = f2bfu(v);
}

// 9b. V transpose with key permutation: within each 64-key block, col
//     c = 4*m + sub holds key m + sub*16 (matches attn P-pack order)
__global__ __launch_bounds__(256) void prep_vt(const float* __restrict__ vbuf,
        unsigned short* __restrict__ vt) {
    int bd = blockIdx.x;               // (b*8+h)*32 + d, 512 blocks
    int b = bd >> 8;
    int rest = bd & 255;
    int h = rest >> 5, d = rest & 31;
    int t = threadIdx.x;
    int blk = t >> 4, m = t & 15;      // 16 key-blocks x 16 m
    int j0 = blk * 64 + m;
    ushort4 o;
    o.x = f2bfu(vbuf[((size_t)(b * NSEQ + j0 +  0)) * 256 + h * 32 + d]);
    o.y = f2bfu(vbuf[((size_t)(b * NSEQ + j0 + 16)) * 256 + h * 32 + d]);
    o.z = f2bfu(vbuf[((size_t)(b * NSEQ + j0 + 32)) * 256 + h * 32 + d]);
    o.w = f2bfu(vbuf[((size_t)(b * NSEQ + j0 + 48)) * 256 + h * 32 + d]);
    *(ushort4*)&vt[(size_t)bd * NSEQ + blk * 64 + 4 * m] = o;
}

// ---------------------------------------------------------------------------
// 10. MFMA flash attention v3: no running max (logits bounded), deferred row
//     sums, exp2, packed b64 P writes via key-permuted LDS columns.
//     Epilogue writes split A' = [hi | hi | lo] bf16 for the final GEMM.
// ---------------------------------------------------------------------------
__global__ __launch_bounds__(256) void attn_v3(
        const unsigned short* __restrict__ Qb,   // [bh][8192][32]
        const unsigned short* __restrict__ Kb,   // [bh][1024][32]
        const unsigned short* __restrict__ Vt,   // [bh][32][1024] key-permuted
        const float* __restrict__ conf,          // [b][1024]
        unsigned short* __restrict__ aout) {     // [16384][768] split
    __shared__ __align__(16) unsigned short Pl[4 * 2304];  // 4 waves * 2*16*72
    const float SC = 0.17677669529663687f * 1.4426950408889634f; // scale*log2e
    const float CL = 1.4426950408889634f;                        // log2e
    int tid  = threadIdx.x;
    int wave = tid >> 6;
    int lane = tid & 63;
    int m15  = lane & 15;
    int quad = lane >> 4;
    int bh = blockIdx.y;
    int b  = bh >> 3;
    int h  = bh & 7;
    int qbase = blockIdx.x * 128 + wave * 32;

    const unsigned short* qp = Qb + ((size_t)bh * NTOK + qbase) * 32;
    bfrag Qa0 = *(const bfrag*)(qp + (size_t)m15 * 32 + quad * 8);
    bfrag Qa1 = *(const bfrag*)(qp + (size_t)(16 + m15) * 32 + quad * 8);

    const unsigned short* kp = Kb + (size_t)bh * NSEQ * 32;
    const unsigned short* vp = Vt + (size_t)bh * 32 * NSEQ;
    const float* cp = conf + b * NSEQ;
    unsigned short* Pw = Pl + wave * 2304;

    f32x4 O[2][2];
    float lrow[2][4];
    #pragma unroll
    for (int t = 0; t < 2; t++) {
        #pragma unroll
        for (int dt = 0; dt < 2; dt++) O[t][dt] = (f32x4){0.f, 0.f, 0.f, 0.f};
        #pragma unroll
        for (int r = 0; r < 4; r++) lrow[t][r] = 0.f;
    }
    f32x4 zero = (f32x4){0.f, 0.f, 0.f, 0.f};

    for (int t0 = 0; t0 < NSEQ; t0 += 64) {
        // ---- S = Q K^T (8 MFMAs) ----
        f32x4 S[2][4];
        #pragma unroll
        for (int sub = 0; sub < 4; sub++) {
            bfrag kf = *(const bfrag*)(kp +
                (size_t)(t0 + sub * 16 + m15) * 32 + quad * 8);
            S[0][sub] = __builtin_amdgcn_mfma_f32_16x16x32_bf16(Qa0, kf, zero, 0, 0, 0);
            S[1][sub] = __builtin_amdgcn_mfma_f32_16x16x32_bf16(Qa1, kf, zero, 0, 0, 0);
        }
        float cf[4];
        #pragma unroll
        for (int sub = 0; sub < 4; sub++) cf[sub] = cp[t0 + sub * 16 + m15] * CL;
        // ---- exp2 softmax numerators; pack P rows (keys {m15,+16,+32,+48}
        //      -> contiguous cols 4*m15, matching Vt's permutation) ----
        #pragma unroll
        for (int t = 0; t < 2; t++) {
            #pragma unroll
            for (int r = 0; r < 4; r++) {
                unsigned int rp[4];
                float fs = 0.f;
                #pragma unroll
                for (int sub = 0; sub < 4; sub++) {
                    float p = exp2f(S[t][sub][r] * SC + cf[sub]);
                    unsigned int rr = rtn16(p);
                    rp[sub] = rr;
                    fs += bits2f(rr & 0xffff0000u);  // l from ROUNDED p
                }
                lrow[t][r] += fs;
                unsigned int d0 = (rp[0] >> 16) | (rp[1] & 0xffff0000u);
                unsigned int d1 = (rp[2] >> 16) | (rp[3] & 0xffff0000u);
                uint2 dd; dd.x = d0; dd.y = d1;
                *(uint2*)&Pw[t * 1152 + (quad * 4 + r) * 72 + 4 * m15] = dd;
            }
        }
        // ---- O += P V (8 MFMAs) ----
        #pragma unroll
        for (int kf2 = 0; kf2 < 2; kf2++) {
            bfrag Pa0 = *(const bfrag*)&Pw[0 * 1152 + m15 * 72 + kf2 * 32 + quad * 8];
            bfrag Pa1 = *(const bfrag*)&Pw[1 * 1152 + m15 * 72 + kf2 * 32 + quad * 8];
            #pragma unroll
            for (int dt = 0; dt < 2; dt++) {
                bfrag vf = *(const bfrag*)(vp +
                    (size_t)(dt * 16 + m15) * NSEQ + t0 + kf2 * 32 + quad * 8);
                O[0][dt] = __builtin_amdgcn_mfma_f32_16x16x32_bf16(Pa0, vf, O[0][dt], 0, 0, 0);
                O[1][dt] = __builtin_amdgcn_mfma_f32_16x16x32_bf16(Pa1, vf, O[1][dt], 0, 0, 0);
            }
        }
    }
    // ---- deferred row-sum reduction (over the 16 key-lanes) ----
    #pragma unroll
    for (int t = 0; t < 2; t++) {
        #pragma unroll
        for (int r = 0; r < 4; r++) {
            float s = lrow[t][r];
            s += __shfl_xor(s, 1, 64);
            s += __shfl_xor(s, 2, 64);
            s += __shfl_xor(s, 4, 64);
            s += __shfl_xor(s, 8, 64);
            lrow[t][r] = s;
        }
    }
    // ---- epilogue: O/l -> split hi/hi/lo bf16 into aout [16384][768] ----
    #pragma unroll
    for (int t = 0; t < 2; t++) {
        #pragma unroll
        for (int r = 0; r < 4; r++) {
            float inv = 1.0f / lrow[t][r];
            int row = b * NTOK + qbase + t * 16 + quad * 4 + r;
            size_t rb = (size_t)row * 768;
            #pragma unroll
            for (int dt = 0; dt < 2; dt++) {
                float o = O[t][dt][r] * inv;
                unsigned int hr = rtn16(o);
                unsigned short hu = hr >> 16;
                float hf = bits2f(hr & 0xffff0000u);
                unsigned short lu = rtn16(o - hf) >> 16;
                int col = h * 32 + dt * 16 + m15;
                aout[rb + col]       = hu;
                aout[rb + 256 + col] = hu;
                aout[rb + 512 + col] = lu;
            }
        }
    }
}

// ---------------------------------------------------------------------------
extern "C" void kernel_launch(void* const* d_in, const int* in_sizes, int n_in,
                              void* d_out, int out_size, void* d_ws, size_t ws_size,
                              hipStream_t stream) {
    const float* x        = (const float*)d_in[0];
    const float* x_source = (const float*)d_in[1];
    const float* loc      = (const float*)d_in[2];
    const float* conf     = (const float*)d_in[3];
    const float* Wq       = (const float*)d_in[4];
    const float* Wk       = (const float*)d_in[5];
    const float* Wv       = (const float*)d_in[6];
    const float* srw      = (const float*)d_in[7];
    const float* srb      = (const float*)d_in[8];
    const float* lnw      = (const float*)d_in[9];
    const float* lnb      = (const float*)d_in[10];
    const float* Wp       = (const float*)d_in[11];
    const float* bp       = (const float*)d_in[12];
    float* out = (float*)d_out;
    float* ws  = (float*)d_ws;

    // ---- workspace layout (float units) ----
    float* feat  = ws;                          // 8,388,608 f (raw scatter sums)
    float* maskr = feat + 8388608;              // 32,768 f
    // feat region reused after recon_fused/conv chain:
    float* qbuf = feat;                                        // 4,194,304 f
    unsigned short* Qbf = (unsigned short*)(feat + 4194304);   // 4,194,304 u16
    unsigned short* Kbf = (unsigned short*)(feat + 6291456);   //   524,288 u16
    unsigned short* Vtb = (unsigned short*)(feat + 6553600);   //   524,288 u16
    // region 2 (overlaid later by aout_split):
    float* r2 = maskr + 32768;
    unsigned short* apatch = (unsigned short*)r2;              // 8,388,608 u16
    unsigned short* wTb    = (unsigned short*)(r2 + 4194304);  // 1,048,576 u16
    unsigned short* xbf    = (unsigned short*)(r2 + 4718592);  // 4,194,304 u16
    unsigned short* aouts  = (unsigned short*)r2;              // 12,582,912 u16 (overlay)
    // region 3 (never overlapped):
    float* xsb  = r2 + 6815744;                 // 524,288 f
    unsigned short* xsbf = (unsigned short*)(xsb + 524288);    // 524,288 u16
    float* kbuf = xsb + 786432;                 // 524,288 f
    float* vbuf = kbuf + 524288;                // 524,288 f
    unsigned short* wqb = (unsigned short*)(vbuf + 524288);    // 65,536 u16
    unsigned short* wkb = wqb + 65536;
    unsigned short* wvb = wkb + 65536;
    unsigned short* wpb = wvb + 65536;                          // 196,608 u16

    // zero scatter accumulators (feat + maskr adjacent)
    hipMemsetAsync(feat, 0, (size_t)(8388608 + 32768) * sizeof(float), stream);

    scatter_k  <<<16384, 256, 0, stream>>>(x_source, loc, feat, maskr);
    recon_fused<<<32768, 256, 0, stream>>>(feat, maskr, apatch);
    wtrans_k   <<<4096,  256, 0, stream>>>(srw, wTb);
    cvt_bf16   <<<4096,  256, 0, stream>>>(x,  xbf);
    cvt_bf16   <<<64,    256, 0, stream>>>(Wq, wqb);
    cvt_bf16   <<<64,    256, 0, stream>>>(Wk, wkb);
    cvt_bf16   <<<64,    256, 0, stream>>>(Wv, wvb);
    prep_wp    <<<256,   256, 0, stream>>>(Wp, wpb);
    init_bias_k<<<2048,  256, 0, stream>>>(xsb, srb);
    // conv as GEMM (2048 x 256 x 4096), split-K 8
    bgemm<<<dim3(2, 16, 8), 256, 0, stream>>>(apatch, wTb, nullptr, xsb,
                                              2048, 256, 4096, 8);
    ln_k<<<2048, 256, 0, stream>>>(xsb, lnw, lnb, xsbf);
    bgemm<<<dim3(2, 16, 1),  256, 0, stream>>>(xsbf, wkb, nullptr, kbuf,
                                               2048, 256, 256, 1);
    bgemm<<<dim3(2, 16, 1),  256, 0, stream>>>(xsbf, wvb, nullptr, vbuf,
                                               2048, 256, 256, 1);
    bgemm<<<dim3(2, 128, 1), 256, 0, stream>>>(xbf, wqb, nullptr, qbuf,
                                               16384, 256, 256, 1);
    prep_qk<<<16384, 256, 0, stream>>>(qbuf, Qbf, 13);
    prep_qk<<<2048,  256, 0, stream>>>(kbuf, Kbf, 10);
    prep_vt<<<512,   256, 0, stream>>>(vbuf, Vtb);
    attn_v3<<<dim3(64, 16), 256, 0, stream>>>(Qbf, Kbf, Vtb, conf, aouts);
    // final projection with fp32-accurate K-expansion split (K=768)
    bgemm<<<dim3(2, 128, 1), 256, 0, stream>>>(aouts, wpb, bp, out,
                                               16384, 256, 768, 1);
}